// Round 1
// baseline (526.459 us; speedup 1.0000x reference)
//
#include <hip/hip_runtime.h>

// MADGraph scoring kernel, MI355X (gfx950).
// One wave (64 lanes) per query. Lane layout: sgrp = lane>>4 (4 sample groups),
// d16 = lane&15 (16 dim-blocks of 8 floats -> 128 dims).
// 4 passes x 4 parallel samples = 16 samples (2 sides x 8).

#define D 128
#define S 8

__global__ __launch_bounds__(256) void madgraph_kernel(
    const int* __restrict__ src, const int* __restrict__ dst,
    const int* __restrict__ mid0, const int* __restrict__ mid1,
    const float* __restrict__ position, const float* __restrict__ src_field,
    const float* __restrict__ dst_field, const float* __restrict__ unc,
    const float* __restrict__ edge, float* __restrict__ out,
    int n_query, int n_nodes)
{
    const int lane = threadIdx.x & 63;
    const int wave = threadIdx.x >> 6;
    const int n = blockIdx.x * 4 + wave;
    if (n >= n_query) return;

    const int d16  = lane & 15;
    const int sgrp = lane >> 4;
    const int dbase = d16 * 8;

    const int sn = src[n];
    const int dn = dst[n];
    const float U = unc[0];

    // Per-query reference rows: 8 floats per lane each, coalesced 512B row reads.
    const float4* pS = (const float4*)(position + (size_t)sn * D + dbase);
    const float4* pD = (const float4*)(position + (size_t)dn * D + dbase);
    const float4* fD = (const float4*)(dst_field + (size_t)dn * D + dbase);
    const float4* fS = (const float4*)(src_field + (size_t)sn * D + dbase);
    const float4 ps0 = pS[0], ps1 = pS[1];
    const float4 pd0 = pD[0], pd1 = pD[1];
    const float4 fd0 = fD[0], fd1 = fD[1];
    const float4 fs0 = fS[0], fs1 = fS[1];

    float logit[4], xs[4];

    #pragma unroll
    for (int p = 0; p < 4; ++p) {
        const int side = p >> 1;            // 0: src side (mid0), 1: dst side (mid1)
        const int s = (p & 1) * 4 + sgrp;   // sample 0..7 on this side

        const int mid = side == 0 ? mid0[(size_t)n * S + s]
                                  : mid1[(size_t)n * S + s];

        const float4* pm = (const float4*)(position + (size_t)mid * D + dbase);
        const float4 m0 = pm[0], m1 = pm[1];

        const float4 r0 = side == 0 ? ps0 : pd0;
        const float4 r1 = side == 0 ? ps1 : pd1;
        const float4 f0 = side == 0 ? fd0 : fs0;
        const float4 f1 = side == 0 ? fd1 : fs1;

        float dot = 0.f, sq = 0.f;
        float t;
        t = r0.x - m0.x; dot += t * f0.x; sq += t * t;
        t = r0.y - m0.y; dot += t * f0.y; sq += t * t;
        t = r0.z - m0.z; dot += t * f0.z; sq += t * t;
        t = r0.w - m0.w; dot += t * f0.w; sq += t * t;
        t = r1.x - m1.x; dot += t * f1.x; sq += t * t;
        t = r1.y - m1.y; dot += t * f1.y; sq += t * t;
        t = r1.z - m1.z; dot += t * f1.z; sq += t * t;
        t = r1.w - m1.w; dot += t * f1.w; sq += t * t;

        // reduce over the 16 dim-lanes (xor masks 1,2,4,8 stay in-group)
        #pragma unroll
        for (int off = 8; off; off >>= 1) {
            dot += __shfl_xor(dot, off, 64);
            sq  += __shfl_xor(sq,  off, 64);
        }

        const float e = side == 0 ? edge[(size_t)mid * n_nodes + dn]
                                  : edge[(size_t)sn * n_nodes + mid];
        logit[p] = dot + U * e;
        xs[p]    = 1.0f - sqrtf(sq);
    }

    // Softmax over 16 samples: 4 in registers, 4 groups across lanes (bits 4-5).
    float m = fmaxf(fmaxf(xs[0], xs[1]), fmaxf(xs[2], xs[3]));
    m = fmaxf(m, __shfl_xor(m, 16, 64));
    m = fmaxf(m, __shfl_xor(m, 32, 64));

    float se = 0.f, sa = 0.f;
    #pragma unroll
    for (int p = 0; p < 4; ++p) {
        const float w = __expf(xs[p] - m);
        se += w;
        sa += w * logit[p];
    }
    se += __shfl_xor(se, 16, 64);
    sa += __shfl_xor(sa, 16, 64);
    se += __shfl_xor(se, 32, 64);
    sa += __shfl_xor(sa, 32, 64);

    if (lane == 0) out[n] = sa / se;
}

extern "C" void kernel_launch(void* const* d_in, const int* in_sizes, int n_in,
                              void* d_out, int out_size, void* d_ws, size_t ws_size,
                              hipStream_t stream)
{
    const int*   src      = (const int*)d_in[0];
    const int*   dst      = (const int*)d_in[1];
    const int*   mid0     = (const int*)d_in[2];
    const int*   mid1     = (const int*)d_in[3];
    const float* position = (const float*)d_in[4];
    const float* srcf     = (const float*)d_in[5];
    const float* dstf     = (const float*)d_in[6];
    const float* unc      = (const float*)d_in[7];
    const float* edge     = (const float*)d_in[8];
    float*       out      = (float*)d_out;

    const int n_query = in_sizes[0];
    const int n_nodes = in_sizes[4] / D;

    const int queries_per_block = 4;   // 256 threads = 4 waves
    const int grid = (n_query + queries_per_block - 1) / queries_per_block;

    madgraph_kernel<<<grid, 256, 0, stream>>>(
        src, dst, mid0, mid1, position, srcf, dstf, unc, edge, out,
        n_query, n_nodes);
}

// Round 2
// 524.130 us; speedup vs baseline: 1.0044x; 1.0044x over previous
//
#include <hip/hip_runtime.h>

// MADGraph scoring kernel, MI355X (gfx950).
// One wave (64 lanes) per query. Lane layout: sgrp = lane>>4 (4 sample groups),
// d16 = lane&15 (16 dim-blocks of 8 floats -> 128 dims).
// R1: all loads issued up front (max MLP), nontemporal edge gathers,
// 4 independent FMA chains + interleaved shuffle reduction.

#define D 128
#define S 8

__global__ __launch_bounds__(256, 4) void madgraph_kernel(
    const int* __restrict__ src, const int* __restrict__ dst,
    const int* __restrict__ mid0, const int* __restrict__ mid1,
    const float* __restrict__ position, const float* __restrict__ src_field,
    const float* __restrict__ dst_field, const float* __restrict__ unc,
    const float* __restrict__ edge, float* __restrict__ out,
    int n_query, int n_nodes)
{
    const int lane = threadIdx.x & 63;
    const int wave = threadIdx.x >> 6;
    const int n = blockIdx.x * 4 + wave;
    if (n >= n_query) return;

    const int d16  = lane & 15;
    const int sgrp = lane >> 4;
    const int dbase = d16 * 8;

    // ---- phase 1: issue EVERY load, no dependent compute in between ----
    const int sn = src[n];
    const int dn = dst[n];
    const float U = unc[0];

    // this group's 4 sample indices (side0: passes 0,1 ; side1: passes 2,3)
    const int m00 = mid0[(size_t)n * S + sgrp];
    const int m01 = mid0[(size_t)n * S + 4 + sgrp];
    const int m10 = mid1[(size_t)n * S + sgrp];
    const int m11 = mid1[(size_t)n * S + 4 + sgrp];

    // edge scalars — random into 400 MB, no reuse: nontemporal to spare LLC
    const float e0 = __builtin_nontemporal_load(edge + (size_t)m00 * n_nodes + dn);
    const float e1 = __builtin_nontemporal_load(edge + (size_t)m01 * n_nodes + dn);
    const float e2 = __builtin_nontemporal_load(edge + (size_t)sn * n_nodes + m10);
    const float e3 = __builtin_nontemporal_load(edge + (size_t)sn * n_nodes + m11);

    // reference rows (coalesced 512 B row reads, L2/LLC-resident tables)
    const float4* pS = (const float4*)(position  + (size_t)sn * D + dbase);
    const float4* pD = (const float4*)(position  + (size_t)dn * D + dbase);
    const float4* fD = (const float4*)(dst_field + (size_t)dn * D + dbase);
    const float4* fS = (const float4*)(src_field + (size_t)sn * D + dbase);
    const float4 ps0 = pS[0], ps1 = pS[1];
    const float4 pd0 = pD[0], pd1 = pD[1];
    const float4 fd0 = fD[0], fd1 = fD[1];
    const float4 fs0 = fS[0], fs1 = fS[1];

    // midpoint rows
    const float4* q0 = (const float4*)(position + (size_t)m00 * D + dbase);
    const float4* q1 = (const float4*)(position + (size_t)m01 * D + dbase);
    const float4* q2 = (const float4*)(position + (size_t)m10 * D + dbase);
    const float4* q3 = (const float4*)(position + (size_t)m11 * D + dbase);
    const float4 a0 = q0[0], a1 = q0[1];
    const float4 b0 = q1[0], b1 = q1[1];
    const float4 c0 = q2[0], c1 = q2[1];
    const float4 g0 = q3[0], g1 = q3[1];

    // ---- phase 2: 4 independent dot/sq chains (ILP) ----
    float dot0 = 0.f, sq0 = 0.f, dot1 = 0.f, sq1 = 0.f;
    float dot2 = 0.f, sq2 = 0.f, dot3 = 0.f, sq3 = 0.f;
    float t;
#define ACC(dotv, sqv, r, m, f) \
    t = r.x - m.x; dotv += t * f.x; sqv += t * t; \
    t = r.y - m.y; dotv += t * f.y; sqv += t * t; \
    t = r.z - m.z; dotv += t * f.z; sqv += t * t; \
    t = r.w - m.w; dotv += t * f.w; sqv += t * t;

    ACC(dot0, sq0, ps0, a0, fd0) ACC(dot0, sq0, ps1, a1, fd1)   // side0 s=sgrp
    ACC(dot1, sq1, ps0, b0, fd0) ACC(dot1, sq1, ps1, b1, fd1)   // side0 s=4+sgrp
    ACC(dot2, sq2, pd0, c0, fs0) ACC(dot2, sq2, pd1, c1, fs1)   // side1 s=sgrp
    ACC(dot3, sq3, pd0, g0, fs0) ACC(dot3, sq3, pd1, g1, fs1)   // side1 s=4+sgrp
#undef ACC

    // reduce over the 16 dim-lanes; 8 independent chains interleaved
    #pragma unroll
    for (int off = 8; off; off >>= 1) {
        dot0 += __shfl_xor(dot0, off, 64); sq0 += __shfl_xor(sq0, off, 64);
        dot1 += __shfl_xor(dot1, off, 64); sq1 += __shfl_xor(sq1, off, 64);
        dot2 += __shfl_xor(dot2, off, 64); sq2 += __shfl_xor(sq2, off, 64);
        dot3 += __shfl_xor(dot3, off, 64); sq3 += __shfl_xor(sq3, off, 64);
    }

    float logit[4], xs[4];
    logit[0] = dot0 + U * e0;  xs[0] = 1.0f - sqrtf(sq0);
    logit[1] = dot1 + U * e1;  xs[1] = 1.0f - sqrtf(sq1);
    logit[2] = dot2 + U * e2;  xs[2] = 1.0f - sqrtf(sq2);
    logit[3] = dot3 + U * e3;  xs[3] = 1.0f - sqrtf(sq3);

    // softmax over 16 samples: 4 in registers, 4 groups across lane bits 4-5
    float m = fmaxf(fmaxf(xs[0], xs[1]), fmaxf(xs[2], xs[3]));
    m = fmaxf(m, __shfl_xor(m, 16, 64));
    m = fmaxf(m, __shfl_xor(m, 32, 64));

    float se = 0.f, sa = 0.f;
    #pragma unroll
    for (int p = 0; p < 4; ++p) {
        const float w = __expf(xs[p] - m);
        se += w;
        sa += w * logit[p];
    }
    se += __shfl_xor(se, 16, 64);
    sa += __shfl_xor(sa, 16, 64);
    se += __shfl_xor(se, 32, 64);
    sa += __shfl_xor(sa, 32, 64);

    if (lane == 0) out[n] = sa / se;
}

extern "C" void kernel_launch(void* const* d_in, const int* in_sizes, int n_in,
                              void* d_out, int out_size, void* d_ws, size_t ws_size,
                              hipStream_t stream)
{
    const int*   src      = (const int*)d_in[0];
    const int*   dst      = (const int*)d_in[1];
    const int*   mid0     = (const int*)d_in[2];
    const int*   mid1     = (const int*)d_in[3];
    const float* position = (const float*)d_in[4];
    const float* srcf     = (const float*)d_in[5];
    const float* dstf     = (const float*)d_in[6];
    const float* unc      = (const float*)d_in[7];
    const float* edge     = (const float*)d_in[8];
    float*       out      = (float*)d_out;

    const int n_query = in_sizes[0];
    const int n_nodes = in_sizes[4] / D;

    const int grid = (n_query + 3) / 4;   // 4 waves (queries) per 256-thread block

    madgraph_kernel<<<grid, 256, 0, stream>>>(
        src, dst, mid0, mid1, position, srcf, dstf, unc, edge, out,
        n_query, n_nodes);
}